// Round 6
// baseline (201.084 us; speedup 1.0000x reference)
//
#include <hip/hip_runtime.h>

#define TOKENS 16384
#define DIM    256
#define NEMB   1024
#define BM     128     // token tile
#define BN     128     // embed tile
#define NSTEP  4       // hi-only bf16 GEMM: K=256 in steps of 64
#define CAP    128     // candidate slots per token
#define MARGIN 8.0f    // >= 2B, B = certified |d2_approx - d2_exact| bound (~2.9)

typedef __attribute__((ext_vector_type(8))) short short8;
typedef __attribute__((ext_vector_type(4))) float f32x4;

__device__ __forceinline__ unsigned short bf16_rn(float f) {
    unsigned int u = __float_as_uint(f);
    u += 0x7fff + ((u >> 16) & 1);
    return (unsigned short)(u >> 16);
}

// ------- prep: bf16-hi of x,E; exact fp32 esq; zero candidate counts -------
__global__ __launch_bounds__(256) void prep_kernel(const float* __restrict__ x,
                                                   const float* __restrict__ E,
                                                   unsigned short* __restrict__ xbf,
                                                   unsigned short* __restrict__ ebf,
                                                   float* __restrict__ esq,
                                                   int* __restrict__ counts) {
    const int tid = blockIdx.x * 256 + threadIdx.x;
    if (tid < TOKENS) counts[tid] = 0;            // re-init every launch (ws poisoned)
    const int wave = tid >> 6;
    const int lane = threadIdx.x & 63;
    #pragma unroll 1
    for (int rr = 0; rr < 4; ++rr) {
        const int row = wave * 4 + rr;                       // 0..17407, wave-uniform
        const bool isE = row >= TOKENS;
        const float* src = isE ? (E + (size_t)(row - TOKENS) * DIM)
                               : (x + (size_t)row * DIM);
        const float4 v = reinterpret_cast<const float4*>(src)[lane];
        const float f[4] = {v.x, v.y, v.z, v.w};
        unsigned long long hv = 0;
        #pragma unroll
        for (int i = 0; i < 4; ++i)
            hv |= (unsigned long long)bf16_rn(f[i]) << (16 * i);
        unsigned short* dst = isE ? (ebf + (size_t)(row - TOKENS) * DIM)
                                  : (xbf + (size_t)row * DIM);
        *reinterpret_cast<unsigned long long*>(dst + 4 * lane) = hv;
        if (isE) {
            float s = fmaf(v.x, v.x, fmaf(v.y, v.y, fmaf(v.z, v.z, v.w * v.w)));
            #pragma unroll
            for (int off = 32; off > 0; off >>= 1) s += __shfl_down(s, off);
            if (lane == 0) esq[row - TOKENS] = s;
        }
    }
}

// ------- hi-only MFMA GEMM + certified candidate collection -------
// R4-proven structure: grid 1024 XCD-swizzled, 128x128 tile, 2x32KB dbuf,
// 4 waves (2x2), wave tile 64x64 = 4x4 frags of 16x16x32 bf16 MFMA.
__global__ __launch_bounds__(256) void vq_mfma(const unsigned short* __restrict__ xbf,
                                               const unsigned short* __restrict__ ebf,
                                               const float* __restrict__ esq,
                                               int* __restrict__ counts,
                                               int* __restrict__ cand) {
    __shared__ unsigned short ls[2][(BM + BN) * 64];   // 2 x 32KB double buffer

    const int t    = threadIdx.x;
    const int lane = t & 63;
    const int w    = t >> 6;             // wave 0..3
    const int wr   = w >> 1, wc = w & 1;
    const int bid  = (int)blockIdx.x;    // T1 XCD swizzle (1024 % 8 == 0, bijective)
    const int lb   = (bid & 7) * 128 + (bid >> 3);
    const int m0   = (lb & 127) * BM;
    const int n0   = (lb >> 7) * BN;

    f32x4 acc[4][4];
    #pragma unroll
    for (int i = 0; i < 4; ++i)
        #pragma unroll
        for (int j = 0; j < 4; ++j) acc[i][j] = (f32x4){0.f, 0.f, 0.f, 0.f};

    const int srow   = lane >> 3;                 // row within 8-row staging group
    const int schunk = (lane & 7) ^ srow;         // pre-swizzled 16B chunk of the 128B row

    auto stage = [&](char* lbase, int s) {        // K-step s: 64 bf16 per row
        #pragma unroll
        for (int c = 0; c < 4; ++c) {
            const int ra = m0 + w * 32 + c * 8 + srow;
            const int rb = n0 + w * 32 + c * 8 + srow;
            const char* ga = (const char*)(xbf + (size_t)ra * DIM + s * 64) + schunk * 16;
            const char* gb = (const char*)(ebf + (size_t)rb * DIM + s * 64) + schunk * 16;
            __builtin_amdgcn_global_load_lds(
                (const __attribute__((address_space(1))) unsigned int*)ga,
                (__attribute__((address_space(3))) unsigned int*)(lbase + (w * 32 + c * 8) * 128),
                16, 0, 0);
            __builtin_amdgcn_global_load_lds(
                (const __attribute__((address_space(1))) unsigned int*)gb,
                (__attribute__((address_space(3))) unsigned int*)(lbase + (BM + w * 32 + c * 8) * 128),
                16, 0, 0);
        }
    };

    auto compute = [&](const char* lbase) {
        const int rA = lane & 15;
        const int g  = lane >> 4;
        #pragma unroll
        for (int kh = 0; kh < 2; ++kh) {
            short8 af[4], bfr[4];
            #pragma unroll
            for (int mf = 0; mf < 4; ++mf) {
                const int row = wr * 64 + mf * 16 + rA;
                const int ch  = (kh * 4 + g) ^ (row & 7);    // read-side un-swizzle
                af[mf] = *(const short8*)(lbase + row * 128 + ch * 16);
            }
            #pragma unroll
            for (int nf = 0; nf < 4; ++nf) {
                const int row = wc * 64 + nf * 16 + rA;
                const int ch  = (kh * 4 + g) ^ (row & 7);
                bfr[nf] = *(const short8*)(lbase + (BM + row) * 128 + ch * 16);
            }
            #pragma unroll
            for (int mf = 0; mf < 4; ++mf)
                #pragma unroll
                for (int nf = 0; nf < 4; ++nf)
                    acc[mf][nf] = __builtin_amdgcn_mfma_f32_16x16x32_bf16(
                        af[mf], bfr[nf], acc[mf][nf], 0, 0, 0);
        }
    };

    // 2-phase pipeline (proven in R4): issue next-tile loads BEFORE compute.
    stage((char*)ls[0], 0);
    __syncthreads();
    #pragma unroll 1
    for (int sp = 0; sp < NSTEP; sp += 2) {
        stage((char*)ls[1], sp + 1);
        compute((char*)ls[0]);
        __syncthreads();
        if (sp < NSTEP - 2) stage((char*)ls[0], sp + 2);
        compute((char*)ls[1]);
        __syncthreads();
    }

    // epilogue: d2a = esq[n] - 2*dot_hi. Pass 1: wave-local per-row min.
    const int g  = lane >> 4;    // C/D: col = lane&15, row = g*4 + reg
    const int cl = lane & 15;
    float eq[4];
    #pragma unroll
    for (int nf = 0; nf < 4; ++nf) eq[nf] = esq[n0 + wc * 64 + nf * 16 + cl];

    float bd[4][4];              // per (mf,j) row: min over this wave's 64 cols
    #pragma unroll
    for (int mf = 0; mf < 4; ++mf)
        #pragma unroll
        for (int j = 0; j < 4; ++j) {
            float m = 3.4e38f;
            #pragma unroll
            for (int nf = 0; nf < 4; ++nf)
                m = fminf(m, fmaf(-2.f, acc[mf][nf][j], eq[nf]));
            bd[mf][j] = m;
        }
    #pragma unroll
    for (int off = 8; off >= 1; off >>= 1)       // butterfly: all 16 cl lanes get min
        #pragma unroll
        for (int mf = 0; mf < 4; ++mf)
            #pragma unroll
            for (int j = 0; j < 4; ++j)
                bd[mf][j] = fminf(bd[mf][j], __shfl_xor(bd[mf][j], off));

    // Pass 2: certified candidate test (threshold = wavemin + MARGIN >= wavemin + 2B
    // guarantees the true argmin is collected by its owning wave).
    #pragma unroll
    for (int mf = 0; mf < 4; ++mf)
        #pragma unroll
        for (int j = 0; j < 4; ++j) {
            const int row = m0 + wr * 64 + mf * 16 + g * 4 + j;
            #pragma unroll
            for (int nf = 0; nf < 4; ++nf) {
                const float d = fmaf(-2.f, acc[mf][nf][j], eq[nf]);
                if (d <= bd[mf][j] + MARGIN) {
                    const int pos = atomicAdd(&counts[row], 1);
                    if (pos < CAP) cand[(size_t)row * CAP + pos] = n0 + wc * 64 + nf * 16 + cl;
                }
            }
        }
}

// ------- exact f64 re-rank of candidates; writes winning index -------
__global__ __launch_bounds__(256) void vq_rerank(const float* __restrict__ x,
                                                 const float* __restrict__ E,
                                                 const int* __restrict__ counts,
                                                 const int* __restrict__ cand,
                                                 int* __restrict__ idxout) {
    const int r    = blockIdx.x * 4 + (threadIdx.x >> 6);   // one wave per token
    const int lane = threadIdx.x & 63;
    const float4 xv = reinterpret_cast<const float4*>(x + (size_t)r * DIM)[lane];

    double best = 1e300;
    int    bestn = 0;
    const int c = counts[r];

    auto eval = [&](int n) {
        const float4 ev = reinterpret_cast<const float4*>(E + (size_t)n * DIM)[lane];
        double s = 0.0;
        { double d = (double)xv.x - (double)ev.x; s += d * d; }
        { double d = (double)xv.y - (double)ev.y; s += d * d; }
        { double d = (double)xv.z - (double)ev.z; s += d * d; }
        { double d = (double)xv.w - (double)ev.w; s += d * d; }
        #pragma unroll
        for (int off = 32; off > 0; off >>= 1) s += __shfl_xor(s, off);
        if (s < best || (s == best && n < bestn)) { best = s; bestn = n; }  // lowest idx
    };

    if (c <= CAP) {
        #pragma unroll 1
        for (int i = 0; i < c; ++i) eval(cand[(size_t)r * CAP + i]);
    } else {
        #pragma unroll 1
        for (int n = 0; n < NEMB; ++n) eval(n);   // overflow fallback (exact, rare)
    }
    if (lane == 0) idxout[r] = bestn;
}

// ------- gather: out = E[idx] (|(x+q)-x - q| << threshold, validated R5) -------
__global__ __launch_bounds__(256) void vq_out(const float* __restrict__ E,
                                              const int* __restrict__ idx,
                                              float* __restrict__ out) {
    const int wave = (blockIdx.x * 256 + threadIdx.x) >> 6;  // 0..4095
    const int lane = threadIdx.x & 63;
    const int r0   = wave * 4;
    int id[4];
    #pragma unroll
    for (int i = 0; i < 4; ++i) id[i] = idx[r0 + i];
    float4 ev[4];
    #pragma unroll
    for (int i = 0; i < 4; ++i)
        ev[i] = reinterpret_cast<const float4*>(E + (size_t)id[i] * DIM)[lane];
    #pragma unroll
    for (int i = 0; i < 4; ++i)
        reinterpret_cast<float4*>(out + (size_t)(r0 + i) * DIM)[lane] = ev[i];
}

extern "C" void kernel_launch(void* const* d_in, const int* in_sizes, int n_in,
                              void* d_out, int out_size, void* d_ws, size_t ws_size,
                              hipStream_t stream) {
    const float* x = (const float*)d_in[0];    // [16,1024,256] fp32
    const float* E = (const float*)d_in[1];    // [1024,256] fp32
    float* out = (float*)d_out;

    // ws: idx 64KB | esq 4KB | counts 64KB | ebf 512KB  (~644KB, under proven use)
    int*   idx    = (int*)d_ws;
    float* esq    = (float*)((char*)d_ws + 65536);
    int*   counts = (int*)((char*)d_ws + 65536 + 4096);
    unsigned short* ebf = (unsigned short*)((char*)d_ws + 65536 + 4096 + 65536);
    // d_out (16 MiB) moonlights as scratch: xbf-hi in first 8 MiB, candidate
    // lists in second 8 MiB; both fully consumed before vq_out overwrites it.
    unsigned short* xbf = (unsigned short*)d_out;
    int* cand = (int*)((char*)d_out + (size_t)TOKENS * DIM * 2);

    prep_kernel<<<(TOKENS + NEMB) / 16, 256, 0, stream>>>(x, E, xbf, ebf, esq, counts);
    vq_mfma<<<1024, 256, 0, stream>>>(xbf, ebf, esq, counts, cand);
    vq_rerank<<<TOKENS / 4, 256, 0, stream>>>(x, E, counts, cand, idx);
    vq_out<<<TOKENS / 16, 256, 0, stream>>>(E, idx, out);
}

// Round 8
// 191.947 us; speedup vs baseline: 1.0476x; 1.0476x over previous
//
#include <hip/hip_runtime.h>

#define TOKENS 16384
#define DIM    256
#define NEMB   1024
#define KB2    512     // bf16 K per matrix row: [hi 0..255 | lo 256..511]
#define BM     128     // token tile
#define BN     128     // embed tile
#define GAPTHR 0.02f   // certified: |d2a - d2exact| << this (3-term split, ~1e-3 worst)
#define SLOWGRID 1024

typedef __attribute__((ext_vector_type(8))) short short8;
typedef __attribute__((ext_vector_type(4))) float f32x4;

__device__ __forceinline__ unsigned fsort(float f) {   // monotone float->u32
    unsigned u = __float_as_uint(f);
    return (u & 0x80000000u) ? ~u : (u | 0x80000000u);
}
__device__ __forceinline__ float funsort(unsigned s) { // inverse of fsort
    unsigned u = (s & 0x80000000u) ? (s & 0x7FFFFFFFu) : ~s;
    return __uint_as_float(u);
}
__device__ __forceinline__ unsigned short bf16_rn(float f) {
    unsigned u = __float_as_uint(f);
    u += 0x7fff + ((u >> 16) & 1);
    return (unsigned short)(u >> 16);
}
__device__ __forceinline__ float bf16_to_f(unsigned short h) {
    return __uint_as_float((unsigned)h << 16);
}

// state[token] = (s1:32 | s2_coarse:22 | n1:10).  CAS merge keeps exact global
// (min1, argmin1) and a LOWER bound on min2 (truncation only shrinks gap -> safe).
__device__ __forceinline__ void upd_state(unsigned long long* p,
                                          unsigned w1, unsigned wn, unsigned w2) {
    const unsigned w2c = w2 >> 10;
    unsigned long long cur = *p;
    while (true) {
        const unsigned a1  = (unsigned)(cur >> 32);
        const unsigned a2c = ((unsigned)cur >> 10) & 0x3FFFFFu;
        const unsigned an  = (unsigned)cur & 1023u;
        if (w1 >= a1 && (w1 >> 10) >= a2c) return;   // no effect (tie-skip safe: gap~0)
        unsigned s1, s2c, n1;
        if (w1 < a1)      { s1 = w1; n1 = wn; s2c = min(w2c, a1 >> 10); }
        else if (w1 > a1) { s1 = a1; n1 = an; s2c = min(a2c, w1 >> 10); }
        else              { s1 = a1; n1 = min(an, wn); s2c = min(min(a2c, w2c), a1 >> 10); }
        const unsigned long long des =
            ((unsigned long long)s1 << 32) | ((unsigned long long)s2c << 10) | n1;
        if (des == cur) return;
        const unsigned long long old = atomicCAS(p, cur, des);
        if (old == cur) return;
        cur = old;
    }
}

// ------- prep: split x,E into bf16 hi/lo; exact fp32 esq; init state/nslow -------
__global__ __launch_bounds__(256) void prep_kernel(const float* __restrict__ x,
                                                   const float* __restrict__ E,
                                                   unsigned short* __restrict__ xbf,
                                                   unsigned short* __restrict__ ebf,
                                                   float* __restrict__ esq,
                                                   unsigned long long* __restrict__ state,
                                                   int* __restrict__ nslow) {
    const int tid = blockIdx.x * 256 + threadIdx.x;
    if (tid < TOKENS) state[tid] = ~0ull;   // (+inf, +inf, n=1023); ws is re-poisoned
    if (tid == 0) *nslow = 0;
    const int wave = tid >> 6;
    const int lane = threadIdx.x & 63;
    #pragma unroll 1
    for (int rr = 0; rr < 4; ++rr) {
        const int row = wave * 4 + rr;                       // 0..17407, wave-uniform
        const bool isE = row >= TOKENS;
        const float* src = isE ? (E + (size_t)(row - TOKENS) * DIM)
                               : (x + (size_t)row * DIM);
        const float4 v = reinterpret_cast<const float4*>(src)[lane];
        const float f[4] = {v.x, v.y, v.z, v.w};
        unsigned long long hv = 0, lv = 0;
        #pragma unroll
        for (int i = 0; i < 4; ++i) {
            const unsigned short h = bf16_rn(f[i]);
            const float r = f[i] - bf16_to_f(h);             // exact (Sterbenz)
            const unsigned short l = bf16_rn(r);
            hv |= (unsigned long long)h << (16 * i);
            lv |= (unsigned long long)l << (16 * i);
        }
        unsigned short* dst = isE ? (ebf + (size_t)(row - TOKENS) * KB2)
                                  : (xbf + (size_t)row * KB2);
        *reinterpret_cast<unsigned long long*>(dst + 4 * lane)       = hv;
        *reinterpret_cast<unsigned long long*>(dst + 256 + 4 * lane) = lv;
        if (isE) {
            float s = fmaf(v.x, v.x, fmaf(v.y, v.y, fmaf(v.z, v.z, v.w * v.w)));
            #pragma unroll
            for (int off = 32; off > 0; off >>= 1) s += __shfl_down(s, off);
            if (lane == 0) esq[row - TOKENS] = s;
        }
    }
}

// ------- 3-term split GEMM, chunked: 4 tiles staged, 96 MFMA per barrier-pair -------
// grid 1024 XCD-swizzled; 4 waves (2x2), wave tile 64x64 = 4x4 frags of 16x16x32.
__global__ __launch_bounds__(256) void vq_mfma(const unsigned short* __restrict__ xbf,
                                               const unsigned short* __restrict__ ebf,
                                               const float* __restrict__ esq,
                                               unsigned long long* __restrict__ state) {
    __shared__ unsigned short ls[4][BM * 64];   // Ah | Al | Bh | Bl, 16KB each

    const int t    = threadIdx.x;
    const int lane = t & 63;
    const int w    = t >> 6;             // wave 0..3
    const int wr   = w >> 1, wc = w & 1;
    const int bid  = (int)blockIdx.x;    // T1 XCD swizzle (1024 % 8 == 0, bijective)
    const int lb   = (bid & 7) * 128 + (bid >> 3);
    const int m0   = (lb & 127) * BM;
    const int n0   = (lb >> 7) * BN;

    f32x4 acc[4][4];
    #pragma unroll
    for (int i = 0; i < 4; ++i)
        #pragma unroll
        for (int j = 0; j < 4; ++j) acc[i][j] = (f32x4){0.f, 0.f, 0.f, 0.f};

    const int srow   = lane >> 3;                 // row within 8-row staging group
    const int schunk = (lane & 7) ^ srow;         // pre-swizzled 16B chunk of the 128B row

    #pragma unroll 1
    for (int c = 0; c < 4; ++c) {                 // 4 K-chunks of 64
        __syncthreads();                          // previous chunk fully consumed
        #pragma unroll
        for (int cc = 0; cc < 4; ++cc) {          // stage Ah, Al, Bh, Bl
            const int rg = w * 32 + cc * 8;       // row-group base (wave-uniform)
            const int ra = m0 + rg + srow;
            const int rb = n0 + rg + srow;
            const char* gah = (const char*)(xbf + (size_t)ra * KB2 +       c * 64) + schunk * 16;
            const char* gal = (const char*)(xbf + (size_t)ra * KB2 + 256 + c * 64) + schunk * 16;
            const char* gbh = (const char*)(ebf + (size_t)rb * KB2 +       c * 64) + schunk * 16;
            const char* gbl = (const char*)(ebf + (size_t)rb * KB2 + 256 + c * 64) + schunk * 16;
            __builtin_amdgcn_global_load_lds(
                (const __attribute__((address_space(1))) unsigned int*)gah,
                (__attribute__((address_space(3))) unsigned int*)((char*)ls[0] + rg * 128), 16, 0, 0);
            __builtin_amdgcn_global_load_lds(
                (const __attribute__((address_space(1))) unsigned int*)gal,
                (__attribute__((address_space(3))) unsigned int*)((char*)ls[1] + rg * 128), 16, 0, 0);
            __builtin_amdgcn_global_load_lds(
                (const __attribute__((address_space(1))) unsigned int*)gbh,
                (__attribute__((address_space(3))) unsigned int*)((char*)ls[2] + rg * 128), 16, 0, 0);
            __builtin_amdgcn_global_load_lds(
                (const __attribute__((address_space(1))) unsigned int*)gbl,
                (__attribute__((address_space(3))) unsigned int*)((char*)ls[3] + rg * 128), 16, 0, 0);
        }
        __syncthreads();                          // drain; then 96 MFMA amortize it

        const int rA = lane & 15;
        const int g  = lane >> 4;
        #pragma unroll
        for (int term = 0; term < 3; ++term) {    // hh, lh, hl
            const char* Ab = (const char*)((term == 1) ? ls[1] : ls[0]);
            const char* Bb = (const char*)((term == 2) ? ls[3] : ls[2]);
            #pragma unroll
            for (int kh = 0; kh < 2; ++kh) {
                short8 af[4], bfr[4];
                #pragma unroll
                for (int mf = 0; mf < 4; ++mf) {
                    const int row = wr * 64 + mf * 16 + rA;
                    const int ch  = (kh * 4 + g) ^ (row & 7);   // read-side un-swizzle
                    af[mf] = *(const short8*)(Ab + row * 128 + ch * 16);
                }
                #pragma unroll
                for (int nf = 0; nf < 4; ++nf) {
                    const int row = wc * 64 + nf * 16 + rA;
                    const int ch  = (kh * 4 + g) ^ (row & 7);
                    bfr[nf] = *(const short8*)(Bb + row * 128 + ch * 16);
                }
                #pragma unroll
                for (int mf = 0; mf < 4; ++mf)
                    #pragma unroll
                    for (int nf = 0; nf < 4; ++nf)
                        acc[mf][nf] = __builtin_amdgcn_mfma_f32_16x16x32_bf16(
                            af[mf], bfr[nf], acc[mf][nf], 0, 0, 0);
            }
        }
    }

    // epilogue: per-row (min1, idx1, min2) over this wave's 64 cols -> CAS state
    const int g  = lane >> 4;    // C/D: col = lane&15, row = g*4 + reg
    const int cl = lane & 15;
    float eq[4];
    #pragma unroll
    for (int nf = 0; nf < 4; ++nf) eq[nf] = esq[n0 + wc * 64 + nf * 16 + cl];

    #pragma unroll
    for (int mf = 0; mf < 4; ++mf)
        #pragma unroll
        for (int j = 0; j < 4; ++j) {
            float v1 = 3.4e38f, v2 = 3.4e38f;
            int   i1 = 0;
            #pragma unroll
            for (int nf = 0; nf < 4; ++nf) {      // ascending n within lane
                const int   n = n0 + wc * 64 + nf * 16 + cl;
                const float d = fmaf(-2.f, acc[mf][nf][j], eq[nf]);
                if (d < v1) { v2 = v1; v1 = d; i1 = n; }
                else        { v2 = fminf(v2, d); }
            }
            #pragma unroll
            for (int off = 8; off >= 1; off >>= 1) {    // 16-lane sorted-pair merge
                const float o1 = __shfl_xor(v1, off);
                const int   oi = __shfl_xor(i1, off);
                const float o2 = __shfl_xor(v2, off);
                const float n2 = fminf(fminf(v2, o2), fmaxf(v1, o1));
                if (o1 < v1 || (o1 == v1 && oi < i1)) { v1 = o1; i1 = oi; }
                v2 = n2;
            }
            if (cl == 0) {
                const int row = m0 + wr * 64 + mf * 16 + g * 4 + j;
                upd_state(&state[row], fsort(v1), (unsigned)i1, fsort(v2));
            }
        }
}

// ------- certified tokens: gather; near-ties: append to slow list -------
__global__ __launch_bounds__(256) void vq_final(const unsigned long long* __restrict__ state,
                                                const float* __restrict__ E,
                                                float* __restrict__ out,
                                                int* __restrict__ slowlist,
                                                int* __restrict__ nslow) {
    const int tok  = blockIdx.x * 4 + (threadIdx.x >> 6);
    const int lane = threadIdx.x & 63;
    const unsigned long long st = state[tok];
    const float d1   = funsort((unsigned)(st >> 32));
    const float d2lb = funsort((((unsigned)st >> 10) & 0x3FFFFFu) << 10);  // <= true min2
    const int   n1   = (int)(st & 1023u);
    if (d2lb - d1 > GAPTHR) {
        const float4 ev = reinterpret_cast<const float4*>(E + (size_t)n1 * DIM)[lane];
        reinterpret_cast<float4*>(out + (size_t)tok * DIM)[lane] = ev;
    } else if (lane == 0) {
        slowlist[atomicAdd(nslow, 1)] = tok;
    }
}

// ------- exact resolve for near-tie tokens: one block per token -------
__global__ __launch_bounds__(256) void vq_slow(const float* __restrict__ x,
                                               const float* __restrict__ E,
                                               const int* __restrict__ slowlist,
                                               const int* __restrict__ nslow,
                                               float* __restrict__ out) {
    __shared__ float  xs[DIM];
    __shared__ double wd[4];
    __shared__ int    wi[4];
    const int cnt = *nslow;
    #pragma unroll 1
    for (int it = blockIdx.x; it < cnt; it += SLOWGRID) {
        const int tok = slowlist[it];
        __syncthreads();                          // xs/wd reuse guard
        xs[threadIdx.x] = x[(size_t)tok * DIM + threadIdx.x];
        __syncthreads();
        double bd = 1e300;
        int    bn = 0;
        #pragma unroll 1
        for (int cgrp = 0; cgrp < 4; ++cgrp) {    // thread owns 4 codes
            const int n = cgrp * 256 + threadIdx.x;
            const float* er = E + (size_t)n * DIM;
            double s = 0.0;
            #pragma unroll 4
            for (int k = 0; k < DIM; k += 4) {
                const float4 ev = *(const float4*)(er + k);
                const double d0 = (double)xs[k + 0] - (double)ev.x;
                const double d1 = (double)xs[k + 1] - (double)ev.y;
                const double d2 = (double)xs[k + 2] - (double)ev.z;
                const double d3 = (double)xs[k + 3] - (double)ev.w;
                s += d0 * d0 + d1 * d1 + d2 * d2 + d3 * d3;
            }
            if (s < bd || (s == bd && n < bn)) { bd = s; bn = n; }  // lowest-idx ties
        }
        #pragma unroll
        for (int off = 32; off > 0; off >>= 1) {
            const double od = __shfl_down(bd, off);
            const int    on = __shfl_down(bn, off);
            if (od < bd || (od == bd && on < bn)) { bd = od; bn = on; }
        }
        const int wv = threadIdx.x >> 6;
        if ((threadIdx.x & 63) == 0) { wd[wv] = bd; wi[wv] = bn; }
        __syncthreads();
        double b = wd[0]; int best = wi[0];
        #pragma unroll
        for (int i = 1; i < 4; ++i)
            if (wd[i] < b || (wd[i] == b && wi[i] < best)) { b = wd[i]; best = wi[i]; }
        out[(size_t)tok * DIM + threadIdx.x] = E[(size_t)best * DIM + threadIdx.x];
    }
}

extern "C" void kernel_launch(void* const* d_in, const int* in_sizes, int n_in,
                              void* d_out, int out_size, void* d_ws, size_t ws_size,
                              hipStream_t stream) {
    const float* x = (const float*)d_in[0];    // [16,1024,256] fp32
    const float* E = (const float*)d_in[1];    // [1024,256] fp32
    float* out = (float*)d_out;

    // ws: state 128KB | esq 4KB | ebf 1MB | slowlist 64KB | nslow  (~1.22MB)
    unsigned long long* state = (unsigned long long*)d_ws;
    float* esq          = (float*)((char*)d_ws + 131072);
    unsigned short* ebf = (unsigned short*)((char*)d_ws + 131072 + 4096);
    int* slowlist       = (int*)((char*)d_ws + 131072 + 4096 + 1048576);
    int* nslow          = (int*)((char*)d_ws + 131072 + 4096 + 1048576 + 65536);
    // x split lives in d_out (16384*512*2B == out bytes exactly); fully consumed
    // by vq_mfma before vq_final/vq_slow overwrite d_out with the result.
    unsigned short* xbf = (unsigned short*)d_out;

    prep_kernel<<<(TOKENS + NEMB) / 16, 256, 0, stream>>>(x, E, xbf, ebf, esq, state, nslow);
    vq_mfma<<<1024, 256, 0, stream>>>(xbf, ebf, esq, state);
    vq_final<<<TOKENS / 4, 256, 0, stream>>>(state, E, out, slowlist, nslow);
    vq_slow<<<SLOWGRID, 256, 0, stream>>>(x, E, slowlist, nslow, out);
}